// Round 1
// 787.846 us; speedup vs baseline: 1.0526x; 1.0526x over previous
//
#include <hip/hip_runtime.h>

// LinearREncoder: concat(x,y) -> relu(W1)->relu(W2)->(aggregate)->W3 -> masked mean
// B=64 N=512 XD=YD=128 DIN=256 HD=4096 RD=1024. Lengths are PREFIX masks.
// R8: token compaction + packed-B-to-registers + A-LDS dbuf pipeline (978us,
// MfmaUtil 40%, conflicts 0, FETCH 1.35GB = H1 x8 XCD refetch).
// R9: H1 stored fp8-e4m3 (A-side of layer2 only; weights stay bf16 so the
// mean-surviving weight-quant error is unchanged). MFMA stays bf16: fp8->bf16
// after ds_read_b64 is EXACT (e4m3 values are representable in bf16). 829us,
// but MODE1 showed SQ_LDS_BANK_CONFLICT=1.03e8 + VALUBusy 36% (decode-heavy).
// R10: (a) fp8-A LDS swizzle fixed: XOR chunk by ((m>>1)&3) instead of (m&3).
//      bank key becomes (m&1,(m>>1)&3)=m&7 (period 8) -> 2 lanes/bank-pair
//      (free) instead of 4-way conflict. Matched on BOTH sides (staging source
//      pre-swizzle + read addr swizzle). (b) decode via
//      v_cvt_scalef32_pk_bf16_fp8 (1 op / 2 elems, exact at scale=1.0):
//      8 -> 4 VALU per fragment, guarded by __has_builtin w/ perm fallback.

using u16 = unsigned short;
using u8 = unsigned char;
typedef float f32x4 __attribute__((ext_vector_type(4)));
typedef short s16x8 __attribute__((ext_vector_type(8)));
typedef float f32x2 __attribute__((ext_vector_type(2)));

__device__ __forceinline__ u16 f2bf(float f) {
  union { float f; unsigned u; } v; v.f = f;
  unsigned r = (v.u + 0x7fffu + ((v.u >> 16) & 1u)) >> 16;  // RNE
  return (u16)r;
}
__device__ __forceinline__ unsigned fbits(float f) {
  union { float f; unsigned u; } v; v.f = f; return v.u;
}

// ---------------- prep kernels ----------------

// lens[b] = sum of mask ints (bool arrives as int32 0/1)
__global__ void count_k(const int* __restrict__ mask, int* __restrict__ lens) {
  int b = blockIdx.x, l = threadIdx.x;  // 64 x 64
  const int4* row = (const int4*)(mask + (size_t)b * 512);
  int4 v0 = row[l];
  int4 v1 = row[l + 64];
  int s = v0.x + v0.y + v0.z + v0.w + v1.x + v1.y + v1.z + v1.w;
  #pragma unroll
  for (int o = 32; o; o >>= 1) s += __shfl_down(s, o);
  if (l == 0) lens[b] = s;
}

// meta[0..64] = prefix offsets, meta[65] = total, meta[66] = NT = ceil(total/128)
__global__ void meta_k(const int* __restrict__ lens, int* __restrict__ meta) {
  if (threadIdx.x == 0) {
    int acc = 0; meta[0] = 0;
    for (int b = 0; b < 64; ++b) { acc += lens[b]; meta[b + 1] = acc; }
    meta[65] = acc;
    meta[66] = (acc + 127) >> 7;
  }
}

// tok2b[i] = batch of compact token i (binary search), 64 for pad
__global__ void tok2b_k(const int* __restrict__ meta, int* __restrict__ tok2b) {
  int i = blockIdx.x * 256 + threadIdx.x;  // grid 128 -> 32768
  int total = meta[65];
  int b = 64;
  if (i < total) {
    int lo = 0, hi = 64;
    while (hi - lo > 1) { int mid = (lo + hi) >> 1; if (meta[mid] <= i) lo = mid; else hi = mid; }
    b = lo;
  }
  tok2b[i] = b;
}

// Compact A: A[m][0:128]=bf16(x[tok m]), A[m][128:256]=bf16(y[tok m]); pad rows 0
__global__ void build_a(const float* __restrict__ x, const float* __restrict__ y,
                        const int* __restrict__ meta, const int* __restrict__ tok2b,
                        u16* __restrict__ A) {
  int i4 = blockIdx.x * 256 + threadIdx.x;  // grid 8192
  int e = i4 * 4;
  int m = e >> 8, c = e & 255;
  int total = meta[65];
  ushort4 o = {0, 0, 0, 0};
  if (m < total) {
    int b = tok2b[m], t = m - meta[b];
    const float* src = (c < 128) ? x + ((size_t)b * 512 + t) * 128 + c
                                 : y + ((size_t)b * 512 + t) * 128 + (c - 128);
    float4 v = *(const float4*)src;
    o.x = f2bf(v.x); o.y = f2bf(v.y); o.z = f2bf(v.z); o.w = f2bf(v.w);
  }
  *(ushort4*)&A[e] = o;
}

// Pack W[K][N] f32 -> P in MFMA-fragment-tile order, bf16.
__global__ void pack_k(const float* __restrict__ W, u16* __restrict__ P,
                       int N, int NKB) {
  long c = (long)blockIdx.x * 256 + threadIdx.x;
  int lane = c & 63; long r = c >> 6;
  int s = r & 1; int j = (r >> 1) & 3; int wn = (r >> 3) & 1;
  long q = r >> 4;
  int ktb = (int)(q % NKB), nt = (int)(q / NKB);
  int k = ktb * 64 + s * 32 + (lane >> 4) * 8;
  int n = nt * 128 + wn * 64 + j * 16 + (lane & 15);
  ushort o[8];
  #pragma unroll
  for (int e = 0; e < 8; ++e) o[e] = f2bf(W[(size_t)(k + e) * N + n]);
  *(uint4*)&P[c * 8] = *(uint4*)o;
}

// Sn[m][k] = bf16(S[m][k] / len[m]) for m<64, else 0
__global__ void sn_k(const float* __restrict__ S, const int* __restrict__ lens,
                     u16* __restrict__ Sn) {
  int i4 = blockIdx.x * 256 + threadIdx.x;  // grid 512
  int e = i4 * 4;
  int m = e >> 12;
  float inv = (m < 64) ? (1.0f / (float)lens[m]) : 0.0f;
  float4 v = *(const float4*)(S + e);
  ushort4 o;
  o.x = f2bf(v.x * inv); o.y = f2bf(v.y * inv);
  o.z = f2bf(v.z * inv); o.w = f2bf(v.w * inv);
  *(ushort4*)&Sn[e] = o;
}

// ---------------- main GEMM ----------------
// C[128x128] = A[128xK] @ B; B pre-packed fragment-tiles -> registers (dbuf);
// A staged to LDS dbuf via global_load_lds. K-loop unrolled 2x, raw s_barrier
// + vmcnt(12) steady-state (A staging is the manually-guarded part; B regs are
// compiler-guarded).
// MODE 0: A bf16, Hout = fp8(relu(acc+b))    (layer 1, compact rows)
// MODE 1: A fp8 (exact-decode to bf16), S[batch] += relu(acc+b) seg-carry pool
// MODE 2: A bf16, Fout += acc (+bias on y=0), rows<64, split-K over blockIdx.y
template <int MODE>
__global__ __launch_bounds__(256, 3) void gemm_k(
    const void* __restrict__ Av, int lda, const u16* __restrict__ BP,
    const float* __restrict__ bias, u8* __restrict__ Hout,
    float* __restrict__ Sout, float* __restrict__ Fout,
    const int* __restrict__ meta, const int* __restrict__ tok2b,
    int K, int Nld, int tile0, int tile_cap) {
  constexpr bool A8 = (MODE == 1);
  __shared__ union {
    u16 a16[2][128 * 64];   // 32KB A dbuf (bf16 modes)
    u8  a8[2][128 * 64];    // 8KB/buf used (fp8 mode)
    u16 outT[128 * 128];    // (unused in fp8 epilogue)
    u8  outT8[128 * 128];   // MODE0 fp8 repack (16KB)
  } sm;

  const int tid = threadIdx.x;
  const int wave = tid >> 6;
  const int lane = tid & 63;
  const int wm = wave >> 1, wn = wave & 1;
  const int quad = lane >> 4, l15 = lane & 15;
  const int NKB = K >> 6;

  int nslots;
  if constexpr (MODE < 2) {
    int tc = meta[66] - tile0;
    tc = tc < 0 ? 0 : (tc > tile_cap ? tile_cap : tc);
    nslots = tc * 32;
  } else {
    nslots = gridDim.x;
  }

  for (int slot = blockIdx.x; slot < nslots; slot += gridDim.x) {
    int mt, n0, k0, kend;
    if constexpr (MODE < 2) {
      mt = slot >> 5; n0 = (slot & 31) << 7; k0 = 0; kend = K;
    } else {
      mt = 0; n0 = slot << 7; k0 = blockIdx.y * 512; kend = k0 + 512;
    }

    f32x4 acc[4][4];
    #pragma unroll
    for (int i = 0; i < 4; i++)
      #pragma unroll
      for (int j = 0; j < 4; j++) acc[i][j] = (f32x4){0.f, 0.f, 0.f, 0.f};

    // A staging ptrs.
    // fp8 mode swizzle (R10): LDS chunk ci = (m = ci>>2, slot j = ci&3) holds
    // global 16B chunk c = j ^ ((m>>1)&3). Bank key on the read side becomes
    // (m&1, (m>>1)&3) = m&7: 16-lane group -> 8 distinct bank-pairs x 2 lanes
    // (free) instead of the 4-way conflict of the (m&3) swizzle.
    const u8* ag8[2];
    const u16* ag16[4];
    if constexpr (A8) {
      #pragma unroll
      for (int il = 0; il < 2; ++il) {
        int ci = (wave * 2 + il) * 64 + lane;   // 512 chunks x 16B = 8KB
        int m = ci >> 2, c = (ci & 3) ^ ((m >> 1) & 3);
        ag8[il] = (const u8*)Av + (size_t)(mt * 128 + m) * lda + c * 16;
      }
    } else {
      #pragma unroll
      for (int il = 0; il < 4; ++il) {
        int ci = (wave * 4 + il) * 64 + lane;
        int m = ci >> 3, c = (ci & 7) ^ (m & 7);
        ag16[il] = (const u16*)Av + (size_t)(mt * 128 + m) * lda + c * 8;
      }
    }
    const u16* bw = BP + (size_t)(n0 >> 7) * NKB * 8192 + wn * 4096 + lane * 8;

    auto stageA = [&](int kt, int buf) {
      if constexpr (A8) {
        #pragma unroll
        for (int il = 0; il < 2; ++il)
          __builtin_amdgcn_global_load_lds(
              (const __attribute__((address_space(1))) void*)(ag8[il] + kt),
              (__attribute__((address_space(3))) void*)(&sm.a8[buf][(wave * 2 + il) * 1024]),
              16, 0, 0);
      } else {
        #pragma unroll
        for (int il = 0; il < 4; ++il)
          __builtin_amdgcn_global_load_lds(
              (const __attribute__((address_space(1))) void*)(ag16[il] + kt),
              (__attribute__((address_space(3))) void*)(&sm.a16[buf][(wave * 4 + il) * 512]),
              16, 0, 0);
      }
    };
    auto loadB = [&](int kt, s16x8* dst) {
      const u16* p = bw + (size_t)(kt >> 6) * 8192;
      #pragma unroll
      for (int j = 0; j < 4; j++)
        #pragma unroll
        for (int s = 0; s < 2; s++)
          dst[j * 2 + s] = *(const s16x8*)(p + j * 1024 + s * 512);
    };
    auto compute = [&](int buf, const s16x8* breg) {
      #pragma unroll
      for (int s = 0; s < 2; ++s) {
        s16x8 af[4];
        #pragma unroll
        for (int i = 0; i < 4; i++) {
          int m = wm * 64 + i * 16 + l15;
          if constexpr (A8) {
            int kc = s * 2 + (quad >> 1);
            int addr = (m * 4 + (kc ^ ((m >> 1) & 3))) * 16 + (quad & 1) * 8;
            int2 d = *(const int2*)&sm.a8[buf][addr];
#if __has_builtin(__builtin_amdgcn_cvt_scalef32_pk_bf16_fp8)
            // Direct fp8->2xbf16 (exact at scale=1.0): 4 VALU per fragment.
            typedef __bf16 bf16x2 __attribute__((ext_vector_type(2)));
            union { bf16x2 h[4]; s16x8 v; } u;
            u.h[0] = __builtin_amdgcn_cvt_scalef32_pk_bf16_fp8(d.x, 1.0f, false);
            u.h[1] = __builtin_amdgcn_cvt_scalef32_pk_bf16_fp8(d.x, 1.0f, true);
            u.h[2] = __builtin_amdgcn_cvt_scalef32_pk_bf16_fp8(d.y, 1.0f, false);
            u.h[3] = __builtin_amdgcn_cvt_scalef32_pk_bf16_fp8(d.y, 1.0f, true);
            af[i] = u.v;
#else
            f32x2 f0 = __builtin_amdgcn_cvt_pk_f32_fp8(d.x, 0);
            f32x2 f1 = __builtin_amdgcn_cvt_pk_f32_fp8(d.x, 1);
            f32x2 f2 = __builtin_amdgcn_cvt_pk_f32_fp8(d.y, 0);
            f32x2 f3 = __builtin_amdgcn_cvt_pk_f32_fp8(d.y, 1);
            int4 u;  // bf16 = high half of f32 (exact for e4m3 values)
            u.x = __builtin_amdgcn_perm(fbits(f0.y), fbits(f0.x), 0x07060302);
            u.y = __builtin_amdgcn_perm(fbits(f1.y), fbits(f1.x), 0x07060302);
            u.z = __builtin_amdgcn_perm(fbits(f2.y), fbits(f2.x), 0x07060302);
            u.w = __builtin_amdgcn_perm(fbits(f3.y), fbits(f3.x), 0x07060302);
            af[i] = *(const s16x8*)&u;
#endif
          } else {
            int c = (s * 4 + quad) ^ (m & 7);
            af[i] = *(const s16x8*)&sm.a16[buf][(m * 8 + c) * 8];
          }
        }
        #pragma unroll
        for (int i = 0; i < 4; i++)
          #pragma unroll
          for (int j = 0; j < 4; j++)
            acc[i][j] = __builtin_amdgcn_mfma_f32_16x16x32_bf16(
                af[i], breg[j * 2 + s], acc[i][j], 0, 0, 0);
      }
    };

    s16x8 breg0[8], breg1[8];
    stageA(k0, 0);
    if (k0 + 64 < kend) stageA(k0 + 64, 1);
    loadB(k0, breg0);

    for (int kt = k0; kt < kend; kt += 128) {  // K % 128 == 0 always
      loadB(kt + 64, breg1);
      __builtin_amdgcn_s_waitcnt(0x0F7C);  // vmcnt(12): A(cur) certainly drained
      __builtin_amdgcn_s_barrier();
      compute(0, breg0);
      __builtin_amdgcn_s_barrier();
      if (kt + 128 < kend) stageA(kt + 128, 0);
      if (kt + 128 < kend) {
        loadB(kt + 128, breg0);
        __builtin_amdgcn_s_waitcnt(0x0F7C);  // vmcnt(12)
      } else {
        __builtin_amdgcn_s_waitcnt(0x0F70);  // vmcnt(0): last iter
      }
      __builtin_amdgcn_s_barrier();
      compute(1, breg1);
      __builtin_amdgcn_s_barrier();
      if (kt + 192 < kend) stageA(kt + 192, 1);
    }
    __syncthreads();

    // epilogues (C/D layout: col = lane&15, row = quad*4 + reg)
    if constexpr (MODE == 0) {
      float bb[4];
      #pragma unroll
      for (int j = 0; j < 4; j++) bb[j] = bias[n0 + wn * 64 + j * 16 + l15];
      #pragma unroll
      for (int i = 0; i < 4; i++)
        #pragma unroll
        for (int j = 0; j < 4; j++) {
          int col = wn * 64 + j * 16 + l15;
          #pragma unroll
          for (int r = 0; r < 4; r++) {
            int row = wm * 64 + i * 16 + quad * 4 + r;
            float v = acc[i][j][r] + bb[j];
            v = v > 0.f ? v : 0.f;
            sm.outT8[row * 128 + col] =
                (u8)(__builtin_amdgcn_cvt_pk_fp8_f32(v, v, 0, false) & 0xff);
          }
        }
      __syncthreads();
      #pragma unroll
      for (int u = 0; u < 4; ++u) {
        int e = u * 256 + tid;
        int row = e >> 3, c16 = (e & 7) * 16;
        *(uint4*)&Hout[(size_t)(mt * 128 + row) * Nld + n0 + c16] =
            *(const uint4*)&sm.outT8[row * 128 + c16];
      }
      __syncthreads();
    } else if constexpr (MODE == 1) {
      float bb[4];
      #pragma unroll
      for (int j = 0; j < 4; j++) bb[j] = bias[n0 + wn * 64 + j * 16 + l15];
      int tb[16];
      const int gbase = tile0 * 128 + mt * 128 + wm * 64 + quad * 4;
      #pragma unroll
      for (int i = 0; i < 4; i++)
        #pragma unroll
        for (int r = 0; r < 4; r++) tb[i * 4 + r] = tok2b[gbase + i * 16 + r];
      #pragma unroll
      for (int j = 0; j < 4; j++) {
        int col = n0 + wn * 64 + j * 16 + l15;
        float sum = 0.f;
        int cb = tb[0];
        #pragma unroll
        for (int idx = 0; idx < 16; ++idx) {
          float t = acc[idx >> 2][j][idx & 3] + bb[j];
          t = t > 0.f ? t : 0.f;
          int b = tb[idx];
          if (b != cb) {
            atomicAdd(&Sout[(size_t)cb * 4096 + col], sum);
            sum = 0.f; cb = b;
          }
          sum += t;
        }
        atomicAdd(&Sout[(size_t)cb * 4096 + col], sum);
      }
    } else {
      float bb[4];
      #pragma unroll
      for (int j = 0; j < 4; j++)
        bb[j] = (blockIdx.y == 0) ? bias[n0 + wn * 64 + j * 16 + l15] : 0.f;
      #pragma unroll
      for (int i = 0; i < 4; i++)
        #pragma unroll
        for (int j = 0; j < 4; j++) {
          int col = wn * 64 + j * 16 + l15;
          #pragma unroll
          for (int r = 0; r < 4; r++) {
            int row = wm * 64 + i * 16 + quad * 4 + r;
            if (row < 64)
              atomicAdd(&Fout[(size_t)row * Nld + n0 + col], acc[i][j][r] + bb[j]);
          }
        }
    }
  }
}

// ---------------- host ----------------
extern "C" void kernel_launch(void* const* d_in, const int* in_sizes, int n_in,
                              void* d_out, int out_size, void* d_ws, size_t ws_size,
                              hipStream_t stream) {
  const float* x  = (const float*)d_in[0];
  const float* y  = (const float*)d_in[1];
  const int* mask = (const int*)d_in[2];
  const float* W1 = (const float*)d_in[3];
  const float* b1 = (const float*)d_in[4];
  const float* W2 = (const float*)d_in[5];
  const float* b2 = (const float*)d_in[6];
  const float* W3 = (const float*)d_in[7];
  const float* b3 = (const float*)d_in[8];
  float* out = (float*)d_out;

  char* ws = (char*)d_ws;
  size_t off = 0;
  auto alloc = [&](size_t bytes) {
    char* p = ws + off;
    off += (bytes + 255) & ~(size_t)255;
    return p;
  };
  int* lens  = (int*)alloc(64 * 4);
  int* meta  = (int*)alloc(70 * 4);
  int* tok2b = (int*)alloc((size_t)32768 * 4);
  float* S   = (float*)alloc((size_t)128 * 4096 * 4);
  u16* Sn    = (u16*)alloc((size_t)128 * 4096 * 2);
  u16* W1P   = (u16*)alloc((size_t)256 * 4096 * 2);
  u16* W2P   = (u16*)alloc((size_t)4096 * 4096 * 2);
  u16* W3P   = (u16*)alloc((size_t)4096 * 1024 * 2);
  u16* Abuf  = (u16*)alloc((size_t)32768 * 256 * 2);
  size_t fixed = off;
  size_t h1_full = (size_t)32768 * 4096;  // 134MB fp8 (256 tiles)
  int nchunks, tile_cap;
  if (ws_size >= fixed + h1_full) { nchunks = 1; tile_cap = 256; }
  else if (ws_size >= fixed + h1_full / 2) { nchunks = 2; tile_cap = 128; }
  else if (ws_size >= fixed + h1_full / 4) { nchunks = 4; tile_cap = 64; }
  else return;
  u8* H1 = (u8*)alloc(h1_full / nchunks);

  hipMemsetAsync(S, 0, (size_t)128 * 4096 * 4, stream);
  hipMemsetAsync(out, 0, (size_t)out_size * 4, stream);
  count_k<<<64, 64, 0, stream>>>(mask, lens);
  meta_k<<<1, 64, 0, stream>>>(lens, meta);
  tok2b_k<<<128, 256, 0, stream>>>(meta, tok2b);
  build_a<<<8192, 256, 0, stream>>>(x, y, meta, tok2b, Abuf);
  pack_k<<<512, 256, 0, stream>>>(W1, W1P, 4096, 4);    // K=256
  pack_k<<<8192, 256, 0, stream>>>(W2, W2P, 4096, 64);  // K=4096
  pack_k<<<2048, 256, 0, stream>>>(W3, W3P, 1024, 64);  // K=4096

  for (int c = 0; c < nchunks; ++c) {
    gemm_k<0><<<dim3(768), 256, 0, stream>>>(
        Abuf + (size_t)c * tile_cap * 128 * 256, 256, W1P, b1, H1,
        nullptr, nullptr, meta, tok2b, 256, 4096, c * tile_cap, tile_cap);
    gemm_k<1><<<dim3(768), 256, 0, stream>>>(
        H1, 4096, W2P, b2, nullptr, S, nullptr,
        meta, tok2b, 4096, 4096, c * tile_cap, tile_cap);
  }
  sn_k<<<512, 256, 0, stream>>>(S, lens, Sn);
  gemm_k<2><<<dim3(8, 8), 256, 0, stream>>>(
      Sn, 4096, W3P, b3, nullptr, nullptr, out,
      meta, tok2b, 4096, 1024, 0, 0);
}